// Round 17
// baseline (348.754 us; speedup 1.0000x reference)
//
#include <hip/hip_runtime.h>
#include <cstdint>

typedef _Float16 f16;
typedef __attribute__((ext_vector_type(2))) _Float16 f16x2;
typedef __attribute__((ext_vector_type(4))) _Float16 f16x4;
typedef __attribute__((ext_vector_type(8))) _Float16 f16x8;
typedef __attribute__((ext_vector_type(4))) float f32x4;

#if defined(__has_builtin)
# if __has_builtin(__builtin_amdgcn_fdot2)
#  define HAVE_FDOT2 1
# endif
#endif

// ---------------- CSR build ----------------

// Per-block inclusive scan; also zeroes cnt for reuse by scatter.
__global__ __launch_bounds__(256) void block_scan_kernel(
    int* __restrict__ cnt, int* __restrict__ rowptr,
    int* __restrict__ partials, int n) {
    __shared__ int lds[256];
    int tid = threadIdx.x;
    int i = blockIdx.x * 256 + tid;
    int v = (i < n) ? cnt[i] : 0;
    lds[tid] = v;
    __syncthreads();
    for (int off = 1; off < 256; off <<= 1) {
        int t = (tid >= off) ? lds[tid - off] : 0;
        __syncthreads();
        lds[tid] += t;
        __syncthreads();
    }
    if (i < n) { rowptr[i + 1] = lds[tid]; cnt[i] = 0; }
    if (tid == 255) partials[blockIdx.x] = lds[255];
}

// Merged: every block scans all nb partials in LDS (exclusive), then adds its
// block's offset to rowptr.
__global__ __launch_bounds__(256) void finalize_scan_kernel(
    int* __restrict__ rowptr, const int* __restrict__ partials, int n, int nb) {
    __shared__ int lds[256];
    int tid = threadIdx.x;
    int v = (tid < nb) ? partials[tid] : 0;
    lds[tid] = v;
    __syncthreads();
    for (int off = 1; off < 256; off <<= 1) {
        int t = (tid >= off) ? lds[tid - off] : 0;
        __syncthreads();
        lds[tid] += t;
        __syncthreads();
    }
    __shared__ int blkoff;
    if (tid == 0) blkoff = (blockIdx.x == 0) ? 0 : lds[blockIdx.x - 1];
    __syncthreads();
    int i = blockIdx.x * 256 + tid;
    if (i < n) rowptr[i + 1] += blkoff;
    if (i == 0) rowptr[0] = 0;
}

__global__ void scatter_kernel(const int* __restrict__ src, const int* __restrict__ dst,
                               const int* __restrict__ rowptr, int* __restrict__ cnt,
                               int* __restrict__ src_sorted, int E) {
    int e = blockIdx.x * blockDim.x + threadIdx.x;
    if (e < E) {
        int d = dst[e];
        int p = rowptr[d] + atomicAdd(&cnt[d], 1);
        src_sorted[p] = src[e];
    }
}

// ---------------- weight prep (all 3 layers) + histogram, one dispatch ----------------

struct PrepArgs {
    const float* Wq[3]; const float* Wk[3]; const float* Wv[3]; const float* Ws[3];
    const float* bq[3]; const float* bk[3]; const float* bv[3]; const float* bs[3];
    f16* Wf[3]; float* bias[3];
    const int* dst; int* cnt; int E;
};

__global__ __launch_bounds__(256) void prep_hist_kernel(PrepArgs a) {
    int idx = blockIdx.x * 256 + threadIdx.x;
    if (idx < 448 * 256) {
        int l, loc, K;
        if (idx < 448 * 128)      { l = 0; loc = idx;              K = 128; }
        else if (idx < 448 * 192) { l = 1; loc = idx - 448 * 128;  K = 64;  }
        else                      { l = 2; loc = idx - 448 * 192;  K = 64;  }
        if (loc < 448) {
            a.bias[l][loc] = (loc < 128) ? a.bq[l][loc]
                           : (loc < 256) ? a.bk[l][loc - 128]
                           : (loc < 384) ? a.bv[l][loc - 256]
                           : a.bs[l][loc - 384];
        }
        int c = loc / K, k = loc - c * K;
        float v;
        if (c < 128)      v = a.Wq[l][k * 128 + c];
        else if (c < 256) v = a.Wk[l][k * 128 + (c - 128)];
        else if (c < 384) v = a.Wv[l][k * 128 + (c - 256)];
        else              v = a.Ws[l][k * 64 + (c - 384)];
        int NK = K >> 5;
        int ct = c >> 6, cf = (c >> 4) & 3, fr = c & 15;
        int ks = k >> 5, fk = (k >> 3) & 3, j = k & 7;
        size_t off = ((size_t)(((ct * 4 + cf) * NK + ks) * 4 + fk) * 16 + fr) * 8 + j;
        a.Wf[l][off] = (f16)v;
    }
    int stride = gridDim.x * 256;
    for (int e = idx; e < a.E; e += stride)
        atomicAdd(&a.cnt[a.dst[e]], 1);
}

// ---------------- B-stationary LDS-free MFMA GEMM, operand-swapped ----------------
// XCD-swizzled 1D grid (8*XR*7 blocks): all 7 ct-blocks of a row-range on one
// XCD (X rows L2-resident). Each wave holds its ct's 16 W-fragments in
// registers and sweeps 4 x 16-row X-tiles.
// OPERAND SWAP: D = mfma(Wf, Xf) = (XW)^T fragment -> each lane owns ONE
// output row (fr) with 4 contiguous cols per cf => epilogue is 4 x 8B f16x4
// stores per tile instead of 16 x 2B scalar stores (4-lane fk-groups tile
// 32B-contiguous row segments). Same fragment loads as before.

template <int K, bool F32IN>
__global__ __launch_bounds__(256) void gemm_qkvs_kernel(
    const void* __restrict__ Xv, const f16* __restrict__ Wf,
    const float* __restrict__ bias, f16* __restrict__ out, int M, int XR) {
    constexpr int NK = K / 32;
    int id = blockIdx.x;
    int xcd = id & 7;
    int g = id >> 3;
    int ct = g % 7;
    int xb = xcd * XR + g / 7;          // row-block index (256 rows each)
    int rowbase0 = xb * 256;
    if (rowbase0 >= M) return;

    int tid = threadIdx.x;
    int lane = tid & 63, wid = tid >> 6;
    int fr = lane & 15, fk = lane >> 4;

    // W fragments for this ct (A-operand): all (cf, ks), resident in registers.
    f16x8 bf[4][NK];
    #pragma unroll
    for (int cf = 0; cf < 4; ++cf) {
        const f16* Wp = Wf + (size_t)(ct * 4 + cf) * NK * 512 + (size_t)lane * 8;
        #pragma unroll
        for (int ks = 0; ks < NK; ++ks)
            bf[cf][ks] = *(const f16x8*)(Wp + (size_t)ks * 512);
    }

    // bias for this lane's 4 cols per cf: cols ct*64 + cf*16 + fk*4 + {0..3}
    float4 bv[4];
    #pragma unroll
    for (int cf = 0; cf < 4; ++cf)
        bv[cf] = *(const float4*)(bias + ct * 64 + cf * 16 + fk * 4);

    int rowbase = rowbase0 + wid * 64;

    #pragma unroll
    for (int t = 0; t < 4; ++t) {
        int arow = rowbase + t * 16 + fr;
        int crow = (arow < M) ? arow : (M - 1);

        f16x8 af[NK];
        if (F32IN) {
            const float* X = (const float*)Xv + (size_t)crow * K;
            #pragma unroll
            for (int ks = 0; ks < NK; ++ks) {
                float4 lo = *(const float4*)(X + ks * 32 + fk * 8);
                float4 hi = *(const float4*)(X + ks * 32 + fk * 8 + 4);
                af[ks] = {(f16)lo.x, (f16)lo.y, (f16)lo.z, (f16)lo.w,
                          (f16)hi.x, (f16)hi.y, (f16)hi.z, (f16)hi.w};
            }
        } else {
            const f16* X = (const f16*)Xv + (size_t)crow * K;
            #pragma unroll
            for (int ks = 0; ks < NK; ++ks)
                af[ks] = *(const f16x8*)(X + ks * 32 + fk * 8);
        }

        f32x4 acc[4] = {};
        #pragma unroll
        for (int ks = 0; ks < NK; ++ks) {
            #pragma unroll
            for (int cf = 0; cf < 4; ++cf)
                acc[cf] = __builtin_amdgcn_mfma_f32_16x16x32_f16(bf[cf][ks], af[ks], acc[cf], 0, 0, 0);
        }

        // lane owns row arow, cols ct*64 + cf*16 + fk*4 + {0..3}
        if (arow < M) {
            f16* orow = out + (size_t)arow * 448 + ct * 64 + fk * 4;
            #pragma unroll
            for (int cf = 0; cf < 4; ++cf) {
                f16x4 o = {(f16)(acc[cf][0] + bv[cf].x),
                           (f16)(acc[cf][1] + bv[cf].y),
                           (f16)(acc[cf][2] + bv[cf].z),
                           (f16)(acc[cf][3] + bv[cf].w)};
                *(f16x4*)(orow + cf * 16) = o;
            }
        }
    }
}

// ---------------- fused per-node softmax attention (no max subtraction) ----------------
// Frozen round-12/15 config (plateau-verified): 12500 blocks x 256 threads,
// 4 waves = 4 nodes. Scores d = q.k/8 bounded (|d| < ~3 by construction) ->
// exp fp32-safe without max-subtraction. lane = (eg:bits3-5, c8:bits0-2);
// 8 edges/iter; both heads per lane; srcs chunk-preloaded, served via __shfl.

__global__ __launch_bounds__(256) void attn_kernel(
    const f16* __restrict__ T,  // [N][448] : q|k|v|s
    const int* __restrict__ rowptr, const int* __restrict__ srcs,
    f16* __restrict__ hout, float* __restrict__ fout, int n, int final_layer) {
    int node = blockIdx.x * 4 + (threadIdx.x >> 6);
    if (node >= n) return;
    int lane = threadIdx.x & 63;
    int c8 = lane & 7, eg = lane >> 3;
    const size_t base = (size_t)node * 448;
    const int co = c8 * 8;

    f16x8 q0 = *(const f16x8*)(T + base + co);
    f16x8 q1 = *(const f16x8*)(T + base + 64 + co);
    float s0 = 0.f, s1 = 0.f;
    float av0[8] = {}, av1[8] = {};

    int beg = rowptr[node], end = rowptr[node + 1];
    int deg = end - beg;

    for (int cbase = 0; cbase < deg; cbase += 64) {
        int chunk = min(64, deg - cbase);
        // one coalesced index load covers up to 64 edges
        int myidx = srcs[min(beg + cbase + lane, end - 1)];

        for (int i0 = 0; i0 < chunk; i0 += 8) {
            int sl = i0 + eg;
            bool valid = (sl < chunk);
            int sidx = __shfl(myidx, valid ? sl : 0);
            const f16* p = T + (size_t)sidx * 448 + co;
            f16x8 k0 = *(const f16x8*)(p + 128);
            f16x8 k1 = *(const f16x8*)(p + 192);
            f16x8 v0 = *(const f16x8*)(p + 256);
            f16x8 v1 = *(const f16x8*)(p + 320);

            float d0 = 0.f, d1 = 0.f;
#ifdef HAVE_FDOT2
            #pragma unroll
            for (int j = 0; j < 4; ++j) {
                f16x2 a0 = {q0[2 * j], q0[2 * j + 1]};
                f16x2 b0 = {k0[2 * j], k0[2 * j + 1]};
                d0 = __builtin_amdgcn_fdot2(a0, b0, d0, false);
                f16x2 a1 = {q1[2 * j], q1[2 * j + 1]};
                f16x2 b1 = {k1[2 * j], k1[2 * j + 1]};
                d1 = __builtin_amdgcn_fdot2(a1, b1, d1, false);
            }
#else
            #pragma unroll
            for (int j = 0; j < 8; ++j) {
                d0 += (float)q0[j] * (float)k0[j];
                d1 += (float)q1[j] * (float)k1[j];
            }
#endif
            d0 += __shfl_xor(d0, 1); d1 += __shfl_xor(d1, 1);
            d0 += __shfl_xor(d0, 2); d1 += __shfl_xor(d1, 2);
            d0 += __shfl_xor(d0, 4); d1 += __shfl_xor(d1, 4);

            float p0 = valid ? __expf(d0 * 0.125f) : 0.f;
            float p1 = valid ? __expf(d1 * 0.125f) : 0.f;
            s0 += p0; s1 += p1;
            #pragma unroll
            for (int j = 0; j < 8; ++j) {
                av0[j] += p0 * (float)v0[j];
                av1[j] += p1 * (float)v1[j];
            }
        }
    }

    // reduce partials over the 8 edge-groups (lane bits 3-5)
    s0 += __shfl_xor(s0, 8);  s1 += __shfl_xor(s1, 8);
    s0 += __shfl_xor(s0, 16); s1 += __shfl_xor(s1, 16);
    s0 += __shfl_xor(s0, 32); s1 += __shfl_xor(s1, 32);
    float inv0 = 1.0f / (s0 + 1e-16f), inv1 = 1.0f / (s1 + 1e-16f);
    float r[8];
    #pragma unroll
    for (int j = 0; j < 8; ++j) {
        float a0 = av0[j], a1 = av1[j];
        a0 += __shfl_xor(a0, 8);  a1 += __shfl_xor(a1, 8);
        a0 += __shfl_xor(a0, 16); a1 += __shfl_xor(a1, 16);
        a0 += __shfl_xor(a0, 32); a1 += __shfl_xor(a1, 32);
        r[j] = 0.5f * (a0 * inv0 + a1 * inv1);  // head mean, lane-local
    }

    if (lane < 8) {  // eg==0: 8 lanes x 8 channels = 64 outputs
        f16x8 sk = *(const f16x8*)(T + base + 384 + co);
        #pragma unroll
        for (int j = 0; j < 8; ++j) r[j] = fmaxf(r[j] + (float)sk[j], 0.f);
        if (final_layer) {
            float4* dst4 = (float4*)(fout + (size_t)node * 64 + co);
            dst4[0] = make_float4(r[0], r[1], r[2], r[3]);
            dst4[1] = make_float4(r[4], r[5], r[6], r[7]);
        } else {
            f16x8 o = {(f16)r[0], (f16)r[1], (f16)r[2], (f16)r[3],
                       (f16)r[4], (f16)r[5], (f16)r[6], (f16)r[7]};
            *(f16x8*)(hout + (size_t)node * 64 + co) = o;
        }
    }
}

// ---------------- launch ----------------

extern "C" void kernel_launch(void* const* d_in, const int* in_sizes, int n_in,
                              void* d_out, int out_size, void* d_ws, size_t ws_size,
                              hipStream_t stream) {
    const float* x = (const float*)d_in[0];
    const int* ei  = (const int*)d_in[1];
    const int N = in_sizes[0] / 128;
    const int E = in_sizes[1] / 2;
    const int* src = ei;
    const int* dst = ei + E;

    char* p = (char*)d_ws;
    int* rowptr   = (int*)p; p += (size_t)(N + 1) * 4;
    int* cnt      = (int*)p; p += (size_t)N * 4;
    int* srcs     = (int*)p; p += (size_t)E * 4;
    int* partials = (int*)p; p += 256 * 4;
    p = (char*)(((uintptr_t)p + 255) & ~(uintptr_t)255);
    f16* Xh   = (f16*)p; p += (size_t)N * 64 * 2;
    f16* QKVS = (f16*)p; p += (size_t)N * 448 * 2;
    f16* Wt0  = (f16*)p; p += (size_t)448 * 128 * 2;
    f16* Wt1  = (f16*)p; p += (size_t)448 * 64 * 2;
    f16* Wt2  = (f16*)p; p += (size_t)448 * 64 * 2;
    float* bias0 = (float*)p; p += 448 * 4;
    float* bias1 = (float*)p; p += 448 * 4;
    float* bias2 = (float*)p; p += 448 * 4;
    if ((size_t)(p - (char*)d_ws) > ws_size) return;

    PrepArgs pa;
    for (int l = 0; l < 3; ++l) {
        pa.Wq[l] = (const float*)d_in[2 + 8 * l];
        pa.bq[l] = (const float*)d_in[3 + 8 * l];
        pa.Wk[l] = (const float*)d_in[4 + 8 * l];
        pa.bk[l] = (const float*)d_in[5 + 8 * l];
        pa.Wv[l] = (const float*)d_in[6 + 8 * l];
        pa.bv[l] = (const float*)d_in[7 + 8 * l];
        pa.Ws[l] = (const float*)d_in[8 + 8 * l];
        pa.bs[l] = (const float*)d_in[9 + 8 * l];
    }
    pa.Wf[0] = Wt0; pa.Wf[1] = Wt1; pa.Wf[2] = Wt2;
    pa.bias[0] = bias0; pa.bias[1] = bias1; pa.bias[2] = bias2;
    pa.dst = dst; pa.cnt = cnt; pa.E = E;

    hipMemsetAsync(cnt, 0, (size_t)N * 4, stream);
    prep_hist_kernel<<<(E + 255) / 256, 256, 0, stream>>>(pa);  // prep (448 blks) + hist (all)

    int nb = (N + 255) / 256;
    block_scan_kernel<<<nb, 256, 0, stream>>>(cnt, rowptr, partials, N);   // also re-zeroes cnt
    finalize_scan_kernel<<<nb, 256, 0, stream>>>(rowptr, partials, N, nb);
    scatter_kernel<<<(E + 255) / 256, 256, 0, stream>>>(src, dst, rowptr, cnt, srcs, E);

    // XCD-swizzled GEMM grid: XR row-groups (256 rows) per XCD, 7 ct each.
    int nxb = (N + 255) / 256;            // 196 active row-blocks
    int XR = (nxb + 7) / 8;               // 25 per XCD (padded; extras return)
    int gemm_blocks = 8 * XR * 7;         // 1400
    f16* Wt[3] = {Wt0, Wt1, Wt2};
    float* bias[3] = {bias0, bias1, bias2};
    for (int l = 0; l < 3; ++l) {
        if (l == 0)
            gemm_qkvs_kernel<128, true><<<gemm_blocks, 256, 0, stream>>>(x, Wt[l], bias[l], QKVS, N, XR);
        else
            gemm_qkvs_kernel<64, false><<<gemm_blocks, 256, 0, stream>>>(Xh, Wt[l], bias[l], QKVS, N, XR);
        attn_kernel<<<(N + 3) / 4, 256, 0, stream>>>(
            QKVS, rowptr, srcs, Xh, (float*)d_out, N, (l == 2) ? 1 : 0);
    }
}

// Round 18
// 333.045 us; speedup vs baseline: 1.0472x; 1.0472x over previous
//
#include <hip/hip_runtime.h>
#include <cstdint>

typedef _Float16 f16;
typedef __attribute__((ext_vector_type(2))) _Float16 f16x2;
typedef __attribute__((ext_vector_type(8))) _Float16 f16x8;
typedef __attribute__((ext_vector_type(4))) float f32x4;

#if defined(__has_builtin)
# if __has_builtin(__builtin_amdgcn_fdot2)
#  define HAVE_FDOT2 1
# endif
#endif

// ---------------- CSR build ----------------

__global__ void hist_kernel(const int* __restrict__ dst, int* __restrict__ cnt, int E) {
    int e = blockIdx.x * blockDim.x + threadIdx.x;
    if (e < E) atomicAdd(&cnt[dst[e]], 1);
}

// Per-block inclusive scan; also zeroes cnt for reuse by scatter.
__global__ __launch_bounds__(256) void block_scan_kernel(
    int* __restrict__ cnt, int* __restrict__ rowptr,
    int* __restrict__ partials, int n) {
    __shared__ int lds[256];
    int tid = threadIdx.x;
    int i = blockIdx.x * 256 + tid;
    int v = (i < n) ? cnt[i] : 0;
    lds[tid] = v;
    __syncthreads();
    for (int off = 1; off < 256; off <<= 1) {
        int t = (tid >= off) ? lds[tid - off] : 0;
        __syncthreads();
        lds[tid] += t;
        __syncthreads();
    }
    if (i < n) { rowptr[i + 1] = lds[tid]; cnt[i] = 0; }
    if (tid == 255) partials[blockIdx.x] = lds[255];
}

// Merged: every block scans all nb partials in LDS (exclusive), then adds its
// block's offset to rowptr.
__global__ __launch_bounds__(256) void finalize_scan_kernel(
    int* __restrict__ rowptr, const int* __restrict__ partials, int n, int nb) {
    __shared__ int lds[256];
    int tid = threadIdx.x;
    int v = (tid < nb) ? partials[tid] : 0;
    lds[tid] = v;
    __syncthreads();
    for (int off = 1; off < 256; off <<= 1) {
        int t = (tid >= off) ? lds[tid - off] : 0;
        __syncthreads();
        lds[tid] += t;
        __syncthreads();
    }
    __shared__ int blkoff;
    if (tid == 0) blkoff = (blockIdx.x == 0) ? 0 : lds[blockIdx.x - 1];
    __syncthreads();
    int i = blockIdx.x * 256 + tid;
    if (i < n) rowptr[i + 1] += blkoff;
    if (i == 0) rowptr[0] = 0;
}

__global__ void scatter_kernel(const int* __restrict__ src, const int* __restrict__ dst,
                               const int* __restrict__ rowptr, int* __restrict__ cnt,
                               int* __restrict__ src_sorted, int E) {
    int e = blockIdx.x * blockDim.x + threadIdx.x;
    if (e < E) {
        int d = dst[e];
        int p = rowptr[d] + atomicAdd(&cnt[d], 1);
        src_sorted[p] = src[e];
    }
}

// ---------------- weight prep (all 3 layers; also zeroes cnt) ----------------

struct PrepArgs {
    const float* Wq[3]; const float* Wk[3]; const float* Wv[3]; const float* Ws[3];
    const float* bq[3]; const float* bk[3]; const float* bv[3]; const float* bs[3];
    f16* Wf[3]; float* bias[3];
    int* cnt; int n;
};

__global__ __launch_bounds__(256) void prep_w_all_kernel(PrepArgs a) {
    int idx = blockIdx.x * 256 + threadIdx.x;
    if (idx < a.n) a.cnt[idx] = 0;     // fold cnt zeroing into this dispatch
    int l, loc, K;
    if (idx < 448 * 128)      { l = 0; loc = idx;              K = 128; }
    else if (idx < 448 * 192) { l = 1; loc = idx - 448 * 128;  K = 64;  }
    else                      { l = 2; loc = idx - 448 * 192;  K = 64;  }
    if (loc < 448) {
        a.bias[l][loc] = (loc < 128) ? a.bq[l][loc]
                       : (loc < 256) ? a.bk[l][loc - 128]
                       : (loc < 384) ? a.bv[l][loc - 256]
                       : a.bs[l][loc - 384];
    }
    int c = loc / K, k = loc - c * K;
    float v;
    if (c < 128)      v = a.Wq[l][k * 128 + c];
    else if (c < 256) v = a.Wk[l][k * 128 + (c - 128)];
    else if (c < 384) v = a.Wv[l][k * 128 + (c - 256)];
    else              v = a.Ws[l][k * 64 + (c - 384)];
    int NK = K >> 5;
    int ct = c >> 6, cf = (c >> 4) & 3, fr = c & 15;
    int ks = k >> 5, fk = (k >> 3) & 3, j = k & 7;
    size_t off = ((size_t)(((ct * 4 + cf) * NK + ks) * 4 + fk) * 16 + fr) * 8 + j;
    a.Wf[l][off] = (f16)v;
}

// ---------------- B-stationary LDS-free MFMA GEMM ----------------
// Grid (M/256, 7): block = 256 rows x 64 cols (one ct). Each wave loads its
// ct's 16 (cf,ks) B-fragments ONCE into registers (16KB, L1-shared by the 4
// waves), then sweeps 4 x 16-row A-tiles. Per-MFMA load traffic: 512B
// (256B A + 256B B); per-block L1-level traffic 32KB. No LDS, no barriers.

template <int K, bool F32IN>
__global__ __launch_bounds__(256) void gemm_qkvs_kernel(
    const void* __restrict__ Xv, const f16* __restrict__ Wf,
    const float* __restrict__ bias, f16* __restrict__ out, int M) {
    constexpr int NK = K / 32;
    int tid = threadIdx.x;
    int lane = tid & 63, wid = tid >> 6;
    int fr = lane & 15, fk = lane >> 4;
    int ct = blockIdx.y;

    // B fragments for this ct: all (cf, ks), resident in registers.
    f16x8 bf[4][NK];
    #pragma unroll
    for (int cf = 0; cf < 4; ++cf) {
        const f16* Wp = Wf + (size_t)(ct * 4 + cf) * NK * 512 + (size_t)lane * 8;
        #pragma unroll
        for (int ks = 0; ks < NK; ++ks)
            bf[cf][ks] = *(const f16x8*)(Wp + (size_t)ks * 512);
    }

    int ocol = ct * 64 + fr;
    float bv[4];
    #pragma unroll
    for (int cf = 0; cf < 4; ++cf) bv[cf] = bias[ocol + cf * 16];

    int rowbase = blockIdx.x * 256 + wid * 64;

    #pragma unroll
    for (int t = 0; t < 4; ++t) {
        int arow = rowbase + t * 16 + fr;
        int crow = (arow < M) ? arow : (M - 1);

        f16x8 af[NK];
        if (F32IN) {
            const float* X = (const float*)Xv + (size_t)crow * K;
            #pragma unroll
            for (int ks = 0; ks < NK; ++ks) {
                float4 lo = *(const float4*)(X + ks * 32 + fk * 8);
                float4 hi = *(const float4*)(X + ks * 32 + fk * 8 + 4);
                af[ks] = {(f16)lo.x, (f16)lo.y, (f16)lo.z, (f16)lo.w,
                          (f16)hi.x, (f16)hi.y, (f16)hi.z, (f16)hi.w};
            }
        } else {
            const f16* X = (const f16*)Xv + (size_t)crow * K;
            #pragma unroll
            for (int ks = 0; ks < NK; ++ks)
                af[ks] = *(const f16x8*)(X + ks * 32 + fk * 8);
        }

        f32x4 acc[4] = {};
        #pragma unroll
        for (int ks = 0; ks < NK; ++ks) {
            #pragma unroll
            for (int cf = 0; cf < 4; ++cf)
                acc[cf] = __builtin_amdgcn_mfma_f32_16x16x32_f16(af[ks], bf[cf][ks], acc[cf], 0, 0, 0);
        }

        int orow0 = rowbase + t * 16 + fk * 4;
        #pragma unroll
        for (int cf = 0; cf < 4; ++cf) {
            #pragma unroll
            for (int r = 0; r < 4; ++r) {
                int gr = orow0 + r;
                if (gr < M) out[(size_t)gr * 448 + ocol + cf * 16] = (f16)(acc[cf][r] + bv[cf]);
            }
        }
    }
}

// ---------------- fused per-node softmax attention (no max subtraction) ----------------
// Frozen plateau config: 12500 blocks x 256 threads, 4 waves = 4 nodes.
// Scores d = q.k/8 bounded (|d| < ~3 by construction) -> exp fp32-safe without
// max-subtraction. lane = (eg:bits3-5, c8:bits0-2); 8 edges/iter; both heads
// per lane; srcs chunk-preloaded, served via __shfl.

__global__ __launch_bounds__(256) void attn_kernel(
    const f16* __restrict__ T,  // [N][448] : q|k|v|s
    const int* __restrict__ rowptr, const int* __restrict__ srcs,
    f16* __restrict__ hout, float* __restrict__ fout, int n, int final_layer) {
    int node = blockIdx.x * 4 + (threadIdx.x >> 6);
    if (node >= n) return;
    int lane = threadIdx.x & 63;
    int c8 = lane & 7, eg = lane >> 3;
    const size_t base = (size_t)node * 448;
    const int co = c8 * 8;

    f16x8 q0 = *(const f16x8*)(T + base + co);
    f16x8 q1 = *(const f16x8*)(T + base + 64 + co);
    float s0 = 0.f, s1 = 0.f;
    float av0[8] = {}, av1[8] = {};

    int beg = rowptr[node], end = rowptr[node + 1];
    int deg = end - beg;

    for (int cbase = 0; cbase < deg; cbase += 64) {
        int chunk = min(64, deg - cbase);
        // one coalesced index load covers up to 64 edges
        int myidx = srcs[min(beg + cbase + lane, end - 1)];

        for (int i0 = 0; i0 < chunk; i0 += 8) {
            int sl = i0 + eg;
            bool valid = (sl < chunk);
            int sidx = __shfl(myidx, valid ? sl : 0);
            const f16* p = T + (size_t)sidx * 448 + co;
            f16x8 k0 = *(const f16x8*)(p + 128);
            f16x8 k1 = *(const f16x8*)(p + 192);
            f16x8 v0 = *(const f16x8*)(p + 256);
            f16x8 v1 = *(const f16x8*)(p + 320);

            float d0 = 0.f, d1 = 0.f;
#ifdef HAVE_FDOT2
            #pragma unroll
            for (int j = 0; j < 4; ++j) {
                f16x2 a0 = {q0[2 * j], q0[2 * j + 1]};
                f16x2 b0 = {k0[2 * j], k0[2 * j + 1]};
                d0 = __builtin_amdgcn_fdot2(a0, b0, d0, false);
                f16x2 a1 = {q1[2 * j], q1[2 * j + 1]};
                f16x2 b1 = {k1[2 * j], k1[2 * j + 1]};
                d1 = __builtin_amdgcn_fdot2(a1, b1, d1, false);
            }
#else
            #pragma unroll
            for (int j = 0; j < 8; ++j) {
                d0 += (float)q0[j] * (float)k0[j];
                d1 += (float)q1[j] * (float)k1[j];
            }
#endif
            d0 += __shfl_xor(d0, 1); d1 += __shfl_xor(d1, 1);
            d0 += __shfl_xor(d0, 2); d1 += __shfl_xor(d1, 2);
            d0 += __shfl_xor(d0, 4); d1 += __shfl_xor(d1, 4);

            float p0 = valid ? __expf(d0 * 0.125f) : 0.f;
            float p1 = valid ? __expf(d1 * 0.125f) : 0.f;
            s0 += p0; s1 += p1;
            #pragma unroll
            for (int j = 0; j < 8; ++j) {
                av0[j] += p0 * (float)v0[j];
                av1[j] += p1 * (float)v1[j];
            }
        }
    }

    // reduce partials over the 8 edge-groups (lane bits 3-5)
    s0 += __shfl_xor(s0, 8);  s1 += __shfl_xor(s1, 8);
    s0 += __shfl_xor(s0, 16); s1 += __shfl_xor(s1, 16);
    s0 += __shfl_xor(s0, 32); s1 += __shfl_xor(s1, 32);
    float inv0 = 1.0f / (s0 + 1e-16f), inv1 = 1.0f / (s1 + 1e-16f);
    float r[8];
    #pragma unroll
    for (int j = 0; j < 8; ++j) {
        float a0 = av0[j], a1 = av1[j];
        a0 += __shfl_xor(a0, 8);  a1 += __shfl_xor(a1, 8);
        a0 += __shfl_xor(a0, 16); a1 += __shfl_xor(a1, 16);
        a0 += __shfl_xor(a0, 32); a1 += __shfl_xor(a1, 32);
        r[j] = 0.5f * (a0 * inv0 + a1 * inv1);  // head mean, lane-local
    }

    if (lane < 8) {  // eg==0: 8 lanes x 8 channels = 64 outputs
        f16x8 sk = *(const f16x8*)(T + base + 384 + co);
        #pragma unroll
        for (int j = 0; j < 8; ++j) r[j] = fmaxf(r[j] + (float)sk[j], 0.f);
        if (final_layer) {
            float4* dst4 = (float4*)(fout + (size_t)node * 64 + co);
            dst4[0] = make_float4(r[0], r[1], r[2], r[3]);
            dst4[1] = make_float4(r[4], r[5], r[6], r[7]);
        } else {
            f16x8 o = {(f16)r[0], (f16)r[1], (f16)r[2], (f16)r[3],
                       (f16)r[4], (f16)r[5], (f16)r[6], (f16)r[7]};
            *(f16x8*)(hout + (size_t)node * 64 + co) = o;
        }
    }
}

// ---------------- launch ----------------

extern "C" void kernel_launch(void* const* d_in, const int* in_sizes, int n_in,
                              void* d_out, int out_size, void* d_ws, size_t ws_size,
                              hipStream_t stream) {
    const float* x = (const float*)d_in[0];
    const int* ei  = (const int*)d_in[1];
    const int N = in_sizes[0] / 128;
    const int E = in_sizes[1] / 2;
    const int* src = ei;
    const int* dst = ei + E;

    char* p = (char*)d_ws;
    int* rowptr   = (int*)p; p += (size_t)(N + 1) * 4;
    int* cnt      = (int*)p; p += (size_t)N * 4;
    int* srcs     = (int*)p; p += (size_t)E * 4;
    int* partials = (int*)p; p += 256 * 4;
    p = (char*)(((uintptr_t)p + 255) & ~(uintptr_t)255);
    f16* Xh   = (f16*)p; p += (size_t)N * 64 * 2;
    f16* QKVS = (f16*)p; p += (size_t)N * 448 * 2;
    f16* Wt0  = (f16*)p; p += (size_t)448 * 128 * 2;
    f16* Wt1  = (f16*)p; p += (size_t)448 * 64 * 2;
    f16* Wt2  = (f16*)p; p += (size_t)448 * 64 * 2;
    float* bias0 = (float*)p; p += 448 * 4;
    float* bias1 = (float*)p; p += 448 * 4;
    float* bias2 = (float*)p; p += 448 * 4;
    if ((size_t)(p - (char*)d_ws) > ws_size) return;

    PrepArgs pa;
    for (int l = 0; l < 3; ++l) {
        pa.Wq[l] = (const float*)d_in[2 + 8 * l];
        pa.bq[l] = (const float*)d_in[3 + 8 * l];
        pa.Wk[l] = (const float*)d_in[4 + 8 * l];
        pa.bk[l] = (const float*)d_in[5 + 8 * l];
        pa.Wv[l] = (const float*)d_in[6 + 8 * l];
        pa.bv[l] = (const float*)d_in[7 + 8 * l];
        pa.Ws[l] = (const float*)d_in[8 + 8 * l];
        pa.bs[l] = (const float*)d_in[9 + 8 * l];
    }
    pa.Wf[0] = Wt0; pa.Wf[1] = Wt1; pa.Wf[2] = Wt2;
    pa.bias[0] = bias0; pa.bias[1] = bias1; pa.bias[2] = bias2;
    pa.cnt = cnt; pa.n = N;

    prep_w_all_kernel<<<448, 256, 0, stream>>>(pa);   // also zeroes cnt

    int nb = (N + 255) / 256;
    hist_kernel<<<(E + 255) / 256, 256, 0, stream>>>(dst, cnt, E);
    block_scan_kernel<<<nb, 256, 0, stream>>>(cnt, rowptr, partials, N);   // also re-zeroes cnt
    finalize_scan_kernel<<<nb, 256, 0, stream>>>(rowptr, partials, N, nb);
    scatter_kernel<<<(E + 255) / 256, 256, 0, stream>>>(src, dst, rowptr, cnt, srcs, E);

    int gx = (N + 255) / 256;
    f16* Wt[3] = {Wt0, Wt1, Wt2};
    float* bias[3] = {bias0, bias1, bias2};
    for (int l = 0; l < 3; ++l) {
        if (l == 0)
            gemm_qkvs_kernel<128, true><<<dim3(gx, 7), 256, 0, stream>>>(x, Wt[l], bias[l], QKVS, N);
        else
            gemm_qkvs_kernel<64, false><<<dim3(gx, 7), 256, 0, stream>>>(Xh, Wt[l], bias[l], QKVS, N);
        attn_kernel<<<(N + 3) / 4, 256, 0, stream>>>(
            QKVS, rowptr, srcs, Xh, (float*)d_out, N, (l == 2) ? 1 : 0);
    }
}